// Round 1
// baseline (1575.347 us; speedup 1.0000x reference)
//
#include <hip/hip_runtime.h>
#include <hip/hip_bf16.h>
#include <stdint.h>

using bf16 = __hip_bfloat16;
typedef short bfrag8 __attribute__((ext_vector_type(8)));
typedef float f32x4 __attribute__((ext_vector_type(4)));

// ---------------- workspace layout (bytes) ----------------
constexpr long OFF_XT   = 0L;          // 3 x [32768][512] bf16 NHWC ; later reused as `weighted` [32768][1536] bf16
constexpr long OFF_WQ   = 100663296L;  // 6 x [512][512] bf16
constexpr long OFF_WK   = 103809024L;
constexpr long OFF_WV   = 106954752L;
constexpr long OFF_WO2  = 110100480L;  // 3 x [512][1024] bf16 (stacked Wo pairs)
constexpr long OFF_FW   = 113246208L;  // [1536][1536] bf16
constexpr long OFF_BO2  = 117964800L;  // [3][512] f32 combined Wo bias
constexpr long OFF_POOL = 117972992L;  // [3][8][512] f32
constexpr long OFF_SE   = 118022144L;  // [3][8][512] f32
constexpr long OFF_QACC = 118071296L;  // [8][4] f32 {zc_depth, sum_rgb, ssq_rgb, zc_lidar}
constexpr long OFF_QC   = 118075392L;  // [512][32768] bf16 ; (QC+KC) reused as cross0 f32
constexpr long OFF_KC   = 151629824L;  // [512][32768] bf16
constexpr long OFF_VH   = 185184256L;  // [32768][512] bf16 ; reused as refined2
constexpr long OFF_SC   = 218738688L;  // [16][64][64][64] f32 score partials
constexpr long OFF_ATT  = 235515904L;  // [64][64][64] bf16 attn
constexpr long OFF_OST  = 236040192L;  // 3 x [32768][1024] bf16 ; later cross1/cross2/refined0/refined1
// total = 437366784 bytes (~417 MB)

__device__ __forceinline__ void mfma_bf16(f32x4& c, bfrag8 a, bfrag8 b) {
  asm("v_mfma_f32_16x16x32_bf16 %0, %1, %2, %0" : "+v"(c) : "v"(a), "v"(b));
}

__device__ __forceinline__ void gload16(const void* g, void* l) {
  __builtin_amdgcn_global_load_lds(
      (__attribute__((address_space(1))) void*)(g),
      (__attribute__((address_space(3))) void*)(l), 16, 0, 0);
}

// =================== input transpose: NCHW f32 -> NHWC bf16 ===================
__global__ __launch_bounds__(256) void transpose_kernel(
    const float* __restrict__ x0, const float* __restrict__ x1,
    const float* __restrict__ x2, bf16* __restrict__ xT)
{
  __shared__ float tile[32][33];
  const int zz = blockIdx.z;           // m*8 + b
  const int m = zz >> 3, b = zz & 7;
  const float* x = (m == 0) ? x0 : (m == 1) ? x1 : x2;
  bf16* y = xT + (long)m * 16777216;
  const int p0 = blockIdx.x * 32, c0 = blockIdx.y * 32;
  const int tx = threadIdx.x, ty = threadIdx.y;
#pragma unroll
  for (int j = 0; j < 4; ++j)
    tile[ty + j * 8][tx] = x[((long)b * 512 + c0 + ty + j * 8) * 4096 + p0 + tx];
  __syncthreads();
#pragma unroll
  for (int j = 0; j < 4; ++j)
    y[((long)b * 4096 + p0 + ty + j * 8) * 512 + c0 + tx] =
        __float2bfloat16(tile[tx][ty + j * 8]);
}

// =================== weight conversion / stacking ===================
__global__ void prep_weights(
    const float* __restrict__ wq, const float* __restrict__ wk,
    const float* __restrict__ wv, const float* __restrict__ wo,
    const float* __restrict__ fw, const float* __restrict__ bo,
    bf16* __restrict__ wqB, bf16* __restrict__ wkB, bf16* __restrict__ wvB,
    bf16* __restrict__ wo2, bf16* __restrict__ fwB, float* __restrict__ bo2)
{
  const long stride = (long)gridDim.x * blockDim.x;
  for (long j = (long)blockIdx.x * blockDim.x + threadIdx.x; j < 2359296; j += stride) {
    fwB[j] = __float2bfloat16(fw[j]);
    if (j < 1572864) {
      wqB[j] = __float2bfloat16(wq[j]);
      wkB[j] = __float2bfloat16(wk[j]);
      wvB[j] = __float2bfloat16(wv[j]);
      const long m = j >> 19, rem = j & 524287, c = rem >> 10, k = rem & 1023;
      const long jj = k >> 9, ci = k & 511;
      wo2[j] = __float2bfloat16(wo[(((m * 2 + jj) * 512 + c) << 9) + ci]);
    }
    if (j < 1536) {
      const long m2 = j >> 9, cc = j & 511;
      bo2[j] = bo[((m2 * 2) << 9) + cc] + bo[((m2 * 2 + 1) << 9) + cc];
    }
  }
}

// =================== per-batch quality stats ===================
__global__ __launch_bounds__(256) void quality_kernel(
    const float* __restrict__ rgb, const float* __restrict__ depth,
    const float* __restrict__ lidar, float* __restrict__ qacc)
{
  const int z = blockIdx.z, b = blockIdx.y, ch = blockIdx.x;
  const float* x = (z == 0) ? depth : (z == 1) ? rgb : lidar;
  const long base = (long)b * 2097152 + (long)ch * 65536;
  float s = 0.f, ss = 0.f, cnt = 0.f;
  for (int i = threadIdx.x; i < 65536; i += 256) {
    const float v = x[base + i];
    if (z == 1) { s += v; ss += v * v; }
    else cnt += (v == 0.0f) ? 1.0f : 0.0f;
  }
  for (int o = 32; o; o >>= 1) {
    s += __shfl_xor(s, o); ss += __shfl_xor(ss, o); cnt += __shfl_xor(cnt, o);
  }
  if ((threadIdx.x & 63) == 0) {
    if (z == 1) { atomicAdd(&qacc[b * 4 + 1], s); atomicAdd(&qacc[b * 4 + 2], ss); }
    else if (z == 0) atomicAdd(&qacc[b * 4 + 0], cnt);
    else atomicAdd(&qacc[b * 4 + 3], cnt);
  }
}

// =================== GEMM core: C[M,N] = A[M,K] * Bt[N,K]^T ===================
template<int BM, int BN>
__device__ __forceinline__ void gemm_core(
    const bf16* __restrict__ A, long lda,
    const bf16* __restrict__ Bt, long ldb,
    int K, long m0, long n0,
    bf16* As, bf16* Bs, f32x4 (&acc)[BM / 32][BN / 32])
{
  constexpr int WM = BM / 2, WN = BN / 2, FM = BM / 32, FN = BN / 32;
  const int t = threadIdx.x;
  const int lane = t & 63, wv = t >> 6;
  const int wr = wv >> 1, wc = wv & 1;
  const int l16 = lane & 15, lk = lane >> 4;
  const int srow = t >> 2;
  const int scol = (t & 3) * 8;
  const bf16* Ag = A + (m0 + srow) * lda + scol;
  const bf16* Bg = Bt + (n0 + srow) * ldb + scol;
  char* AsB = (char*)As;
  char* BsB = (char*)Bs;
  const int aoff = wv * 1024;
  for (int kk = 0; kk < K; kk += 32) {
#pragma unroll
    for (int it = 0; it < BM / 64; ++it)
      gload16(Ag + (long)it * 64 * lda + kk, AsB + it * 4096 + aoff);
#pragma unroll
    for (int it = 0; it < BN / 64; ++it)
      gload16(Bg + (long)it * 64 * ldb + kk, BsB + it * 4096 + aoff);
    __syncthreads();
    bfrag8 af[FM], bfr[FN];
#pragma unroll
    for (int m = 0; m < FM; ++m)
      af[m] = *(const bfrag8*)(AsB + ((wr * WM + m * 16 + l16) * 32 + lk * 8) * 2);
#pragma unroll
    for (int n = 0; n < FN; ++n)
      bfr[n] = *(const bfrag8*)(BsB + ((wc * WN + n * 16 + l16) * 32 + lk * 8) * 2);
#pragma unroll
    for (int m = 0; m < FM; ++m)
#pragma unroll
      for (int n = 0; n < FN; ++n)
        mfma_bf16(acc[m][n], af[m], bfr[n]);
    __syncthreads();
  }
}

// EPI: 0 = bf16 C, bias by row ; 1 = bf16 C, bias by col ;
//      2 = f32 C + bias[col] + residual from NCHW f32 (512ch) ; 3 = f32 NCHW-transposed out + bias[col]
template<int EPI>
__global__ __launch_bounds__(256, 2) void gemm_bt(
    const bf16* __restrict__ A, long lda,
    const bf16* __restrict__ Bt, long ldb,
    void* __restrict__ Cv, long ldc, int K,
    const float* __restrict__ bias, const float* __restrict__ resid)
{
  __shared__ __align__(16) bf16 As[128 * 32];
  __shared__ __align__(16) bf16 Bs[128 * 32];
  f32x4 acc[4][4];
#pragma unroll
  for (int m = 0; m < 4; ++m)
#pragma unroll
    for (int n = 0; n < 4; ++n)
      acc[m][n] = f32x4{0.f, 0.f, 0.f, 0.f};
  const long m0 = (long)blockIdx.x * 128, n0 = (long)blockIdx.y * 128;
  gemm_core<128, 128>(A, lda, Bt, ldb, K, m0, n0, As, Bs, acc);

  const int t = threadIdx.x;
  const int lane = t & 63, wv = t >> 6;
  const int wr = wv >> 1, wc = wv & 1;
  const int l16 = lane & 15, lk = lane >> 4;
#pragma unroll
  for (int m = 0; m < 4; ++m) {
    const long gr0 = m0 + wr * 64 + m * 16 + lk * 4;
#pragma unroll
    for (int n = 0; n < 4; ++n) {
      const long gc = n0 + wc * 64 + n * 16 + l16;
      if constexpr (EPI == 0) {
        bf16* Cb = (bf16*)Cv;
#pragma unroll
        for (int i = 0; i < 4; ++i)
          Cb[(gr0 + i) * ldc + gc] = __float2bfloat16(acc[m][n][i] + bias[gr0 + i]);
      } else if constexpr (EPI == 1) {
        bf16* Cb = (bf16*)Cv;
        const float bb = bias[gc];
#pragma unroll
        for (int i = 0; i < 4; ++i)
          Cb[(gr0 + i) * ldc + gc] = __float2bfloat16(acc[m][n][i] + bb);
      } else if constexpr (EPI == 2) {
        float* Cf = (float*)Cv;
        const long b = gr0 >> 12, p = gr0 & 4095;
        const float bb = bias[gc];
        const float4 r4 = *(const float4*)(resid + b * 2097152L + gc * 4096L + p);
#pragma unroll
        for (int i = 0; i < 4; ++i)
          Cf[(gr0 + i) * ldc + gc] = acc[m][n][i] + bb + (&r4.x)[i];
      } else {
        float* Cf = (float*)Cv;
        const long b = gr0 >> 12, p = gr0 & 4095;
        const float bb = bias[gc];
        float4 o4;
        o4.x = acc[m][n][0] + bb; o4.y = acc[m][n][1] + bb;
        o4.z = acc[m][n][2] + bb; o4.w = acc[m][n][3] + bb;
        *(float4*)(Cf + b * (ldc * 4096L) + gc * 4096L + p) = o4;
      }
    }
  }
}

// =================== PV: O'[p, d] = sum_e V'[p, e] * attn[d, e] ===================
__global__ __launch_bounds__(256, 2) void pv_kernel(
    const bf16* __restrict__ V, const bf16* __restrict__ attn,
    bf16* __restrict__ O, int jcol)
{
  __shared__ __align__(16) bf16 As[128 * 32];
  __shared__ __align__(16) bf16 Bs[64 * 32];
  const int bh = blockIdx.y, b = bh >> 3, h = bh & 7;
  const bf16* A = V + (long)b * 4096 * 512 + h * 64;
  const bf16* Bt = attn + (long)bh * 4096;
  f32x4 acc[4][2];
#pragma unroll
  for (int m = 0; m < 4; ++m)
#pragma unroll
    for (int n = 0; n < 2; ++n)
      acc[m][n] = f32x4{0.f, 0.f, 0.f, 0.f};
  const long m0 = (long)blockIdx.x * 128;
  gemm_core<128, 64>(A, 512, Bt, 64, 64, m0, 0, As, Bs, acc);

  const int t = threadIdx.x;
  const int lane = t & 63, wv = t >> 6;
  const int wr = wv >> 1, wc = wv & 1;
  const int l16 = lane & 15, lk = lane >> 4;
  bf16* Cb = O + (long)b * 4096 * 1024 + jcol + h * 64;
#pragma unroll
  for (int m = 0; m < 4; ++m) {
    const long gr0 = m0 + wr * 64 + m * 16 + lk * 4;
#pragma unroll
    for (int n = 0; n < 2; ++n) {
      const int gc = wc * 32 + n * 16 + l16;
#pragma unroll
      for (int i = 0; i < 4; ++i)
        Cb[(gr0 + i) * 1024 + gc] = __float2bfloat16(acc[m][n][i]);
    }
  }
}

// =================== scores: S[d,e] = sum_p Q[d,p] K[e,p] (split-K partials) ===================
__global__ __launch_bounds__(64) void scores_kernel(
    const bf16* __restrict__ Q, const bf16* __restrict__ K, float* __restrict__ part)
{
  const int lane = threadIdx.x;
  const int l16 = lane & 15, lk = lane >> 4;
  const int kc = blockIdx.x;   // 0..15
  const int bh = blockIdx.y;   // 0..63
  const int b = bh >> 3, h = bh & 7;
  const long ld = 32768;
  const bf16* Qb = Q + (long)(h * 64) * ld + (long)b * 4096 + kc * 256;
  const bf16* Kb = K + (long)(h * 64) * ld + (long)b * 4096 + kc * 256;
  f32x4 acc[4][4];
#pragma unroll
  for (int m = 0; m < 4; ++m)
#pragma unroll
    for (int n = 0; n < 4; ++n)
      acc[m][n] = f32x4{0.f, 0.f, 0.f, 0.f};
  for (int ks = 0; ks < 256; ks += 32) {
    bfrag8 a[4], bb[4];
#pragma unroll
    for (int m = 0; m < 4; ++m)
      a[m] = *(const bfrag8*)(Qb + (long)(m * 16 + l16) * ld + ks + lk * 8);
#pragma unroll
    for (int n = 0; n < 4; ++n)
      bb[n] = *(const bfrag8*)(Kb + (long)(n * 16 + l16) * ld + ks + lk * 8);
#pragma unroll
    for (int m = 0; m < 4; ++m)
#pragma unroll
      for (int n = 0; n < 4; ++n)
        mfma_bf16(acc[m][n], a[m], bb[n]);
  }
  float* P = part + ((long)kc * 64 + bh) * 4096;
#pragma unroll
  for (int m = 0; m < 4; ++m)
#pragma unroll
    for (int n = 0; n < 4; ++n)
#pragma unroll
      for (int i = 0; i < 4; ++i)
        P[(m * 16 + lk * 4 + i) * 64 + n * 16 + l16] = acc[m][n][i];
}

// =================== softmax over e (row length 64, wave per row) ===================
__global__ __launch_bounds__(256) void softmax_kernel(
    const float* __restrict__ part, bf16* __restrict__ attn)
{
  const int t = threadIdx.x, lane = t & 63, wv = t >> 6;
  const int r = blockIdx.x * 4 + wv;
  const int bh = blockIdx.y;
  float s = 0.f;
#pragma unroll
  for (int kc = 0; kc < 16; ++kc)
    s += part[((long)kc * 64 + bh) * 4096 + r * 64 + lane];
  s *= 0.125f;  // hd^-0.5, hd=64
  float mx = s;
  for (int o = 32; o; o >>= 1) mx = fmaxf(mx, __shfl_xor(mx, o));
  const float e = expf(s - mx);
  float sum = e;
  for (int o = 32; o; o >>= 1) sum += __shfl_xor(sum, o);
  attn[((long)bh * 64 + r) * 64 + lane] = __float2bfloat16(e / sum);
}

// =================== SE pooling / MLP ===================
__global__ __launch_bounds__(512) void se_pool(
    const float* __restrict__ c0, const float* __restrict__ c1,
    const float* __restrict__ c2, float* __restrict__ pooled)
{
  const int m = blockIdx.z, b = blockIdx.y, pc = blockIdx.x;
  const float* cr = (m == 0) ? c0 : (m == 1) ? c1 : c2;
  const int c = threadIdx.x;
  float s = 0.f;
  const float* base = cr + ((long)b * 4096 + pc * 512) * 512 + c;
  for (int pp = 0; pp < 512; ++pp) s += base[(long)pp * 512];
  atomicAdd(&pooled[((long)m * 8 + b) * 512 + c], s);
}

__global__ __launch_bounds__(512) void se_mlp(
    const float* __restrict__ pooled,
    const float* __restrict__ W1, const float* __restrict__ b1,
    const float* __restrict__ W2, const float* __restrict__ b2,
    float* __restrict__ se)
{
  const int b = blockIdx.x, m = blockIdx.y;
  __shared__ float y[32];
  const int t = threadIdx.x;
  if (t < 32) {
    float s = b1[m * 32 + t];
    const float* w = W1 + (long)(m * 32 + t) * 512;
    const float* p = pooled + ((long)m * 8 + b) * 512;
    for (int c = 0; c < 512; ++c) s += w[c] * (p[c] * (1.0f / 4096.0f));
    y[t] = fmaxf(s, 0.0f);
  }
  __syncthreads();
  float s = b2[m * 512 + t];
  const float* w2 = W2 + (long)(m * 512 + t) * 32;
#pragma unroll
  for (int j = 0; j < 32; ++j) s += w2[j] * y[j];
  se[((long)m * 8 + b) * 512 + t] = 1.0f / (1.0f + expf(-s));
}

// =================== refined = l2norm_c(cross * se) -> bf16 ===================
__global__ __launch_bounds__(256) void refine_kernel(
    const float* __restrict__ cr0, const float* __restrict__ cr1,
    const float* __restrict__ cr2, const float* __restrict__ se,
    bf16* __restrict__ rf0, bf16* __restrict__ rf1, bf16* __restrict__ rf2)
{
  const int g = blockIdx.x * 4 + (threadIdx.x >> 6);
  const int lane = threadIdx.x & 63;
  const int m = g >> 15;
  const int pix = g & 32767;
  const int b = pix >> 12;
  const float* cr = (m == 0) ? cr0 : (m == 1) ? cr1 : cr2;
  bf16* rf = (m == 0) ? rf0 : (m == 1) ? rf1 : rf2;
  const int c0 = lane * 8;
  const float4 v0 = *(const float4*)(cr + (long)pix * 512 + c0);
  const float4 v1 = *(const float4*)(cr + (long)pix * 512 + c0 + 4);
  const float* sp = se + ((long)m * 8 + b) * 512 + c0;
  const float4 s0 = *(const float4*)(sp);
  const float4 s1 = *(const float4*)(sp + 4);
  float w[8] = {v0.x * s0.x, v0.y * s0.y, v0.z * s0.z, v0.w * s0.w,
                v1.x * s1.x, v1.y * s1.y, v1.z * s1.z, v1.w * s1.w};
  float ss = 0.f;
#pragma unroll
  for (int i = 0; i < 8; ++i) ss += w[i] * w[i];
  for (int o = 32; o; o >>= 1) ss += __shfl_xor(ss, o);
  const float inv = 1.0f / (sqrtf(ss) + 1e-6f);
  __align__(16) bf16 tmp[8];
#pragma unroll
  for (int i = 0; i < 8; ++i) tmp[i] = __float2bfloat16(w[i] * inv);
  *(bfrag8*)(rf + (long)pix * 512 + c0) = *(const bfrag8*)tmp;
}

// =================== gate (alpha) + weighted concat ===================
__global__ __launch_bounds__(256) void gate_kernel(
    const bf16* __restrict__ rf0, const bf16* __restrict__ rf1,
    const bf16* __restrict__ rf2, const float* __restrict__ gw,
    const float* __restrict__ gb, const float* __restrict__ qacc,
    bf16* __restrict__ weighted)
{
  const int g = blockIdx.x * 4 + (threadIdx.x >> 6);
  const int lane = threadIdx.x & 63;
  const int b = g >> 12;
  const bf16* rfs[3] = {rf0, rf1, rf2};
  float a0 = 0.f, a1 = 0.f, a2 = 0.f;
#pragma unroll
  for (int m = 0; m < 3; ++m) {
    const bf16* rp = rfs[m] + (long)g * 512;
#pragma unroll
    for (int j = 0; j < 8; ++j) {
      const int c = j * 64 + lane;
      const float v = __bfloat162float(rp[c]);
      a0 += gw[0 * 1539 + m * 512 + c] * v;
      a1 += gw[1 * 1539 + m * 512 + c] * v;
      a2 += gw[2 * 1539 + m * 512 + c] * v;
    }
  }
  for (int o = 32; o; o >>= 1) {
    a0 += __shfl_xor(a0, o); a1 += __shfl_xor(a1, o); a2 += __shfl_xor(a2, o);
  }
  const float N = 2097152.0f;
  const float q0 = qacc[b * 4 + 0] / N;
  const float q1 = (qacc[b * 4 + 2] - qacc[b * 4 + 1] * qacc[b * 4 + 1] / N) / (N - 1.0f);
  const float q2 = qacc[b * 4 + 3] / N;
  float al[3];
  const float av[3] = {a0, a1, a2};
#pragma unroll
  for (int gg = 0; gg < 3; ++gg) {
    const float s = av[gg] + gb[gg] + gw[gg * 1539 + 1536] * q0 +
                    gw[gg * 1539 + 1537] * q1 + gw[gg * 1539 + 1538] * q2;
    al[gg] = 1.0f / (1.0f + expf(-s));
  }
#pragma unroll
  for (int m = 0; m < 3; ++m) {
    const bf16* rp = rfs[m] + (long)g * 512;
    bf16* wp = weighted + (long)g * 1536 + m * 512;
#pragma unroll
    for (int j = 0; j < 8; ++j) {
      const int c = j * 64 + lane;
      wp[c] = __float2bfloat16(__bfloat162float(rp[c]) * al[m]);
    }
  }
}

// =================== host launch ===================
extern "C" void kernel_launch(void* const* d_in, const int* in_sizes, int n_in,
                              void* d_out, int out_size, void* d_ws, size_t ws_size,
                              hipStream_t stream)
{
  (void)in_sizes; (void)n_in; (void)out_size; (void)ws_size;
  const float* rgb   = (const float*)d_in[0];
  const float* depth = (const float*)d_in[1];
  const float* lidar = (const float*)d_in[2];
  const float* wq  = (const float*)d_in[3];
  const float* bq  = (const float*)d_in[4];
  const float* wk  = (const float*)d_in[5];
  const float* bk  = (const float*)d_in[6];
  const float* wvw = (const float*)d_in[7];
  const float* bv  = (const float*)d_in[8];
  const float* wo  = (const float*)d_in[9];
  const float* bo  = (const float*)d_in[10];
  const float* seW1 = (const float*)d_in[11];
  const float* seb1 = (const float*)d_in[12];
  const float* seW2 = (const float*)d_in[13];
  const float* seb2 = (const float*)d_in[14];
  const float* gw  = (const float*)d_in[15];
  const float* gb  = (const float*)d_in[16];
  const float* fw  = (const float*)d_in[17];
  const float* fb  = (const float*)d_in[18];

  char* ws = (char*)d_ws;
  bf16*  xT   = (bf16*)(ws + OFF_XT);
  bf16*  wqB  = (bf16*)(ws + OFF_WQ);
  bf16*  wkB  = (bf16*)(ws + OFF_WK);
  bf16*  wvB  = (bf16*)(ws + OFF_WV);
  bf16*  wo2  = (bf16*)(ws + OFF_WO2);
  bf16*  fwB  = (bf16*)(ws + OFF_FW);
  float* bo2  = (float*)(ws + OFF_BO2);
  float* pooled = (float*)(ws + OFF_POOL);
  float* seB  = (float*)(ws + OFF_SE);
  float* qacc = (float*)(ws + OFF_QACC);
  bf16*  Qc   = (bf16*)(ws + OFF_QC);
  bf16*  Kc   = (bf16*)(ws + OFF_KC);
  bf16*  Vh   = (bf16*)(ws + OFF_VH);
  float* part = (float*)(ws + OFF_SC);
  bf16*  attnB = (bf16*)(ws + OFF_ATT);
  bf16*  Ost  = (bf16*)(ws + OFF_OST);

  // zero atomic accumulators (pooled + se + qacc region)
  (void)hipMemsetAsync(ws + OFF_POOL, 0, 102400, stream);

  transpose_kernel<<<dim3(128, 16, 24), dim3(32, 8), 0, stream>>>(rgb, depth, lidar, xT);
  prep_weights<<<2048, 256, 0, stream>>>(wq, wk, wvw, wo, fw, bo, wqB, wkB, wvB, wo2, fwB, bo2);
  quality_kernel<<<dim3(32, 8, 3), 256, 0, stream>>>(rgb, depth, lidar, qacc);

  static const int QM[6] = {0, 0, 1, 1, 2, 2};
  static const int KM[6] = {1, 2, 0, 2, 0, 1};
  for (int i = 0; i < 6; ++i) {
    const bf16* xq = xT + (long)QM[i] * 16777216;
    const bf16* xk = xT + (long)KM[i] * 16777216;
    // Q, K projections -> channel-major [512][32768]
    gemm_bt<0><<<dim3(4, 256), 256, 0, stream>>>(wqB + (long)i * 262144, 512, xq, 512,
                                                 Qc, 32768, 512, bq + i * 512, nullptr);
    gemm_bt<0><<<dim3(4, 256), 256, 0, stream>>>(wkB + (long)i * 262144, 512, xk, 512,
                                                 Kc, 32768, 512, bk + i * 512, nullptr);
    // V projection -> NHWC [32768][512]
    gemm_bt<1><<<dim3(256, 4), 256, 0, stream>>>(xk, 512, wvB + (long)i * 262144, 512,
                                                 Vh, 512, 512, bv + i * 512, nullptr);
    scores_kernel<<<dim3(16, 64), 64, 0, stream>>>(Qc, Kc, part);
    softmax_kernel<<<dim3(16, 64), 256, 0, stream>>>(part, attnB);
    pv_kernel<<<dim3(32, 64), 256, 0, stream>>>(Vh, attnB,
                                                Ost + (long)(i >> 1) * 33554432, (i & 1) * 512);
  }

  float* cross[3] = {(float*)(ws + OFF_QC), (float*)(ws + OFF_OST),
                     (float*)(ws + OFF_OST + 67108864L)};
  for (int m = 0; m < 3; ++m) {
    gemm_bt<2><<<dim3(256, 4), 256, 0, stream>>>(Ost + (long)m * 33554432, 1024,
                                                 wo2 + (long)m * 524288, 1024,
                                                 cross[m], 512, 1024,
                                                 bo2 + m * 512, (const float*)d_in[m]);
  }

  se_pool<<<dim3(8, 8, 3), 512, 0, stream>>>(cross[0], cross[1], cross[2], pooled);
  se_mlp<<<dim3(8, 3), 512, 0, stream>>>(pooled, seW1, seb1, seW2, seb2, seB);

  bf16* rf0 = (bf16*)(ws + OFF_OST + 134217728L);
  bf16* rf1 = (bf16*)(ws + OFF_OST + 134217728L + 33554432L);
  bf16* rf2 = (bf16*)(ws + OFF_VH);
  refine_kernel<<<24576, 256, 0, stream>>>(cross[0], cross[1], cross[2], seB, rf0, rf1, rf2);

  bf16* weighted = (bf16*)(ws + OFF_XT);
  gate_kernel<<<8192, 256, 0, stream>>>(rf0, rf1, rf2, gw, gb, qacc, weighted);

  gemm_bt<3><<<dim3(256, 12), 256, 0, stream>>>(weighted, 1536, fwB, 1536,
                                                d_out, 1536, 1536, fb, nullptr);
}

// Round 2
// 1315.251 us; speedup vs baseline: 1.1978x; 1.1978x over previous
//
#include <hip/hip_runtime.h>
#include <hip/hip_bf16.h>
#include <stdint.h>

using bf16 = __hip_bfloat16;
typedef short bfrag8 __attribute__((ext_vector_type(8)));
typedef float f32x4 __attribute__((ext_vector_type(4)));

// ---------------- workspace layout (bytes) ----------------
constexpr long OFF_XT   = 0L;           // 3 x [32768][512] bf16 NHWC
constexpr long OFF_XC   = 100663296L;   // 3 x [512][32768] bf16 channel-major
constexpr long OFF_WQ   = 201326592L;   // 6 x [512][512] bf16
constexpr long OFF_WK   = 204472320L;
constexpr long OFF_WV2  = 207618048L;   // 3 x [1024][512] bf16 stacked Wv
constexpr long OFF_WO2  = 210763776L;   // 3 x [512][1024] bf16 stacked Wo
constexpr long OFF_FW   = 213909504L;   // [1536][1536] bf16
constexpr long OFF_BO2  = 218628096L;   // [3][512] f32
constexpr long OFF_BV2  = 218634240L;   // [3][1024] f32
constexpr long OFF_POOL = 218646528L;   // [3][8][512] f32   (memset from here)
constexpr long OFF_SE   = 218695680L;   // [3][8][512] f32
constexpr long OFF_QACC = 218744832L;   // [8][4] f32 (+pad to 1024)
constexpr long OFF_CS   = 218745856L;   // [3][8][512] f32 column sums (memset to here+49152)
constexpr long OFF_GB   = 218795008L;   // [3][8][512][512] bf16 Gram
constexpr long OFF_ATT  = 231377920L;   // [6][8][8][64][64] bf16
constexpr long OFF_VST  = 234523648L;   // 3 x [32768][1024] bf16 ; later cross f32 3x[32768][512]
// total = 435850240
// aliases: Ost = [0, 201326592) (3 x [32768][1024] bf16) after xT/xC dead
//          rf0/1/2 = 0 / 33554432 / 67108864 ; weighted = 100663296 (96 MB)

__device__ __forceinline__ void mfma_bf16(f32x4& c, bfrag8 a, bfrag8 b) {
  asm("v_mfma_f32_16x16x32_bf16 %0, %1, %2, %0" : "+v"(c) : "v"(a), "v"(b));
}

__device__ __forceinline__ void gload16(const void* g, void* l) {
  __builtin_amdgcn_global_load_lds(
      (__attribute__((address_space(1))) void*)(g),
      (__attribute__((address_space(3))) void*)(l), 16, 0, 0);
}

__device__ __forceinline__ float bf2f(short s) {
  union { uint32_t u; float f; } cv;
  cv.u = ((uint32_t)(unsigned short)s) << 16;
  return cv.f;
}

// =================== input transpose: NCHW f32 -> NHWC + channel-major bf16 ===================
__global__ __launch_bounds__(256) void transpose_kernel(
    const float* __restrict__ x0, const float* __restrict__ x1,
    const float* __restrict__ x2, bf16* __restrict__ xT, bf16* __restrict__ xC)
{
  __shared__ float tile[32][33];
  const int zz = blockIdx.z;           // m*8 + b
  const int m = zz >> 3, b = zz & 7;
  const float* x = (m == 0) ? x0 : (m == 1) ? x1 : x2;
  bf16* y = xT + (long)m * 16777216;
  bf16* y2 = xC + (long)m * 16777216;
  const int p0 = blockIdx.x * 32, c0 = blockIdx.y * 32;
  const int tx = threadIdx.x, ty = threadIdx.y;
#pragma unroll
  for (int j = 0; j < 4; ++j) {
    const float v = x[((long)b * 512 + c0 + ty + j * 8) * 4096 + p0 + tx];
    tile[ty + j * 8][tx] = v;
    y2[(long)(c0 + ty + j * 8) * 32768 + (long)b * 4096 + p0 + tx] = __float2bfloat16(v);
  }
  __syncthreads();
#pragma unroll
  for (int j = 0; j < 4; ++j)
    y[((long)b * 4096 + p0 + ty + j * 8) * 512 + c0 + tx] =
        __float2bfloat16(tile[tx][ty + j * 8]);
}

// =================== weight conversion / stacking ===================
__global__ void prep_weights(
    const float* __restrict__ wq, const float* __restrict__ wk,
    const float* __restrict__ wv, const float* __restrict__ wo,
    const float* __restrict__ fw, const float* __restrict__ bo,
    const float* __restrict__ bv,
    bf16* __restrict__ wqB, bf16* __restrict__ wkB, bf16* __restrict__ wv2,
    bf16* __restrict__ wo2, bf16* __restrict__ fwB,
    float* __restrict__ bo2, float* __restrict__ bv2)
{
  const int L0[3] = {2, 0, 1}, L1[3] = {4, 5, 3};
  const long stride = (long)gridDim.x * blockDim.x;
  for (long j = (long)blockIdx.x * blockDim.x + threadIdx.x; j < 2359296; j += stride) {
    fwB[j] = __float2bfloat16(fw[j]);
    if (j < 1572864) {
      wqB[j] = __float2bfloat16(wq[j]);
      wkB[j] = __float2bfloat16(wk[j]);
      const long m = j >> 19, rem = j & 524287;
      {  // wo2[m][c (512)][k (1024)], k = jj*512 + ci
        const long c = rem >> 10, k = rem & 1023, jj = k >> 9, ci = k & 511;
        wo2[j] = __float2bfloat16(wo[(((m * 2 + jj) * 512 + c) << 9) + ci]);
      }
      {  // wv2[m][row (1024)][k (512)]
        const long row = rem >> 9, k = rem & 511;
        const int im = (row < 512) ? L0[m] : L1[m];
        wv2[j] = __float2bfloat16(wv[((long)(im * 512 + (row & 511)) << 9) + k]);
      }
    }
    if (j < 1536) {
      const long m2 = j >> 9, cc = j & 511;
      bo2[j] = bo[((m2 * 2) << 9) + cc] + bo[((m2 * 2 + 1) << 9) + cc];
    }
    if (j < 3072) {
      const long m3 = j >> 10, row = j & 1023;
      const int im = (row < 512) ? L0[m3] : L1[m3];
      bv2[j] = bv[im * 512 + (row & 511)];
    }
  }
}

// =================== per-batch quality stats ===================
__global__ __launch_bounds__(256) void quality_kernel(
    const float* __restrict__ rgb, const float* __restrict__ depth,
    const float* __restrict__ lidar, float* __restrict__ qacc)
{
  const int z = blockIdx.z, b = blockIdx.y, ch = blockIdx.x;
  const float* x = (z == 0) ? depth : (z == 1) ? rgb : lidar;
  const long base = (long)b * 2097152 + (long)ch * 65536;
  float s = 0.f, ss = 0.f, cnt = 0.f;
  for (int i = threadIdx.x; i < 65536; i += 256) {
    const float v = x[base + i];
    if (z == 1) { s += v; ss += v * v; }
    else cnt += (v == 0.0f) ? 1.0f : 0.0f;
  }
  for (int o = 32; o; o >>= 1) {
    s += __shfl_xor(s, o); ss += __shfl_xor(ss, o); cnt += __shfl_xor(cnt, o);
  }
  if ((threadIdx.x & 63) == 0) {
    if (z == 1) { atomicAdd(&qacc[b * 4 + 1], s); atomicAdd(&qacc[b * 4 + 2], ss); }
    else if (z == 0) atomicAdd(&qacc[b * 4 + 0], cnt);
    else atomicAdd(&qacc[b * 4 + 3], cnt);
  }
}

// =================== column sums of xT (for score bias corrections) ===================
__global__ __launch_bounds__(256) void colsum_kernel(
    const bf16* __restrict__ xT, float* __restrict__ cs)
{
  const int pc = blockIdx.x, b = blockIdx.y, m = blockIdx.z;
  const bf16* base = xT + (long)m * 16777216 + ((long)b * 4096 + pc * 256) * 512;
  const int t = threadIdx.x;
  float s0 = 0.f, s1 = 0.f;
  for (int r = 0; r < 256; ++r) {
    s0 += __bfloat162float(base[(long)r * 512 + t]);
    s1 += __bfloat162float(base[(long)r * 512 + 256 + t]);
  }
  atomicAdd(&cs[(m * 8 + b) * 512 + t], s0);
  atomicAdd(&cs[(m * 8 + b) * 512 + 256 + t], s1);
}

// =================== GEMM core: C[M,N] = A[M,K] * Bt[N,K]^T ===================
template<int BM, int BN>
__device__ __forceinline__ void gemm_core(
    const bf16* __restrict__ A, long lda,
    const bf16* __restrict__ Bt, long ldb,
    int K, long m0, long n0,
    bf16* As, bf16* Bs, f32x4 (&acc)[BM / 32][BN / 32])
{
  constexpr int WM = BM / 2, WN = BN / 2, FM = BM / 32, FN = BN / 32;
  const int t = threadIdx.x;
  const int lane = t & 63, wv = t >> 6;
  const int wr = wv >> 1, wc = wv & 1;
  const int l16 = lane & 15, lk = lane >> 4;
  const int srow = t >> 2;
  const int scol = (t & 3) * 8;
  const bf16* Ag = A + (m0 + srow) * lda + scol;
  const bf16* Bg = Bt + (n0 + srow) * ldb + scol;
  char* AsB = (char*)As;
  char* BsB = (char*)Bs;
  const int aoff = wv * 1024;
  for (int kk = 0; kk < K; kk += 32) {
#pragma unroll
    for (int it = 0; it < BM / 64; ++it)
      gload16(Ag + (long)it * 64 * lda + kk, AsB + it * 4096 + aoff);
#pragma unroll
    for (int it = 0; it < BN / 64; ++it)
      gload16(Bg + (long)it * 64 * ldb + kk, BsB + it * 4096 + aoff);
    __syncthreads();
    bfrag8 af[FM], bfr[FN];
#pragma unroll
    for (int m = 0; m < FM; ++m)
      af[m] = *(const bfrag8*)(AsB + ((wr * WM + m * 16 + l16) * 32 + lk * 8) * 2);
#pragma unroll
    for (int n = 0; n < FN; ++n)
      bfr[n] = *(const bfrag8*)(BsB + ((wc * WN + n * 16 + l16) * 32 + lk * 8) * 2);
#pragma unroll
    for (int m = 0; m < FM; ++m)
#pragma unroll
      for (int n = 0; n < FN; ++n)
        mfma_bf16(acc[m][n], af[m], bfr[n]);
    __syncthreads();
  }
}

// EPI: 1 = bf16 C, bias by col ; 2 = f32 C + bias[col] + residual from NCHW f32 (512ch) ;
//      3 = f32 NCHW-transposed out + bias[col]
template<int EPI>
__global__ __launch_bounds__(256, 2) void gemm_bt(
    const bf16* __restrict__ A, long lda,
    const bf16* __restrict__ Bt, long ldb,
    void* __restrict__ Cv, long ldc, int K,
    const float* __restrict__ bias, const float* __restrict__ resid)
{
  __shared__ __align__(16) bf16 As[128 * 32];
  __shared__ __align__(16) bf16 Bs[128 * 32];
  f32x4 acc[4][4];
#pragma unroll
  for (int m = 0; m < 4; ++m)
#pragma unroll
    for (int n = 0; n < 4; ++n)
      acc[m][n] = f32x4{0.f, 0.f, 0.f, 0.f};
  const long m0 = (long)blockIdx.x * 128, n0 = (long)blockIdx.y * 128;
  gemm_core<128, 128>(A, lda, Bt, ldb, K, m0, n0, As, Bs, acc);

  const int t = threadIdx.x;
  const int lane = t & 63, wv = t >> 6;
  const int wr = wv >> 1, wc = wv & 1;
  const int l16 = lane & 15, lk = lane >> 4;
#pragma unroll
  for (int m = 0; m < 4; ++m) {
    const long gr0 = m0 + wr * 64 + m * 16 + lk * 4;
#pragma unroll
    for (int n = 0; n < 4; ++n) {
      const long gc = n0 + wc * 64 + n * 16 + l16;
      if constexpr (EPI == 1) {
        bf16* Cb = (bf16*)Cv;
        const float bb = bias[gc];
#pragma unroll
        for (int i = 0; i < 4; ++i)
          Cb[(gr0 + i) * ldc + gc] = __float2bfloat16(acc[m][n][i] + bb);
      } else if constexpr (EPI == 2) {
        float* Cf = (float*)Cv;
        const long b = gr0 >> 12, p = gr0 & 4095;
        const float bb = bias[gc];
        const float4 r4 = *(const float4*)(resid + b * 2097152L + gc * 4096L + p);
#pragma unroll
        for (int i = 0; i < 4; ++i)
          Cf[(gr0 + i) * ldc + gc] = acc[m][n][i] + bb + (&r4.x)[i];
      } else {
        float* Cf = (float*)Cv;
        const long b = gr0 >> 12, p = gr0 & 4095;
        const float bb = bias[gc];
        float4 o4;
        o4.x = acc[m][n][0] + bb; o4.y = acc[m][n][1] + bb;
        o4.z = acc[m][n][2] + bb; o4.w = acc[m][n][3] + bb;
        *(float4*)(Cf + b * (ldc * 4096L) + gc * 4096L + p) = o4;
      }
    }
  }
}

// =================== Gram: G[i,j] = sum_p xA[p,i] xB[p,j], bf16 out ===================
__global__ __launch_bounds__(256, 2) void gram_kernel(
    const bf16* __restrict__ xC, bf16* __restrict__ Gb)
{
  __shared__ __align__(16) bf16 As[128 * 32];
  __shared__ __align__(16) bf16 Bs[128 * 32];
  const int z = blockIdx.z;
  const int pair = z >> 3, b = z & 7;
  const int A1[3] = {0, 0, 1}, A2[3] = {1, 2, 2};
  const bf16* A = xC + (long)A1[pair] * 16777216 + b * 4096;
  const bf16* Bt = xC + (long)A2[pair] * 16777216 + b * 4096;
  f32x4 acc[4][4];
#pragma unroll
  for (int m = 0; m < 4; ++m)
#pragma unroll
    for (int n = 0; n < 4; ++n)
      acc[m][n] = f32x4{0.f, 0.f, 0.f, 0.f};
  const long m0 = (long)blockIdx.x * 128, n0 = (long)blockIdx.y * 128;
  gemm_core<128, 128>(A, 32768, Bt, 32768, 4096, m0, n0, As, Bs, acc);
  bf16* C = Gb + (long)z * 262144;
  const int t = threadIdx.x;
  const int lane = t & 63, wv = t >> 6;
  const int wr = wv >> 1, wc = wv & 1;
  const int l16 = lane & 15, lk = lane >> 4;
#pragma unroll
  for (int m = 0; m < 4; ++m) {
    const long gr0 = m0 + wr * 64 + m * 16 + lk * 4;
#pragma unroll
    for (int n = 0; n < 4; ++n) {
      const long gc = n0 + wc * 64 + n * 16 + l16;
#pragma unroll
      for (int i = 0; i < 4; ++i)
        C[(gr0 + i) * 512 + gc] = __float2bfloat16(acc[m][n][i]);
    }
  }
}

// =================== scores+softmax: S = Wq G Wk^T (or transposed form) ===================
__global__ __launch_bounds__(256, 2) void scores_kernel(
    const bf16* __restrict__ wqB, const bf16* __restrict__ wkB,
    const bf16* __restrict__ Gb, const float* __restrict__ colsum,
    const float* __restrict__ bq, const float* __restrict__ bk,
    bf16* __restrict__ attnB)
{
  __shared__ __align__(16) bf16 RtS[64 * 520];  // R^T bf16 ; later aliased as S f32 [64][68]
  __shared__ float uv[128];
  const int h = blockIdx.x, b = blockIdx.y, i = blockIdx.z;
  const int qm = i >> 1, jj = i & 1;
  const int km = jj ? (qm == 2 ? 1 : 2) : (qm == 0 ? 1 : 0);
  const int lo = qm < km ? qm : km, hi = qm < km ? km : qm;
  const int pair = lo + hi - 1;
  const int trans = qm > km;
  const bf16* G = Gb + ((long)(pair * 8 + b)) * 262144;
  const bf16* Wq_h = wqB + (long)i * 262144 + h * 64 * 512;
  const bf16* Wk_h = wkB + (long)i * 262144 + h * 64 * 512;
  const bf16* WA = trans ? Wk_h : Wq_h;   // step-B A operand
  const bf16* WB = trans ? Wq_h : Wk_h;   // step-A Bt operand
  const int t = threadIdx.x, lane = t & 63, wv = t >> 6;
  const int l16 = lane & 15, lk = lane >> 4;

  // u[d] = Wq_h[d,:] . colsum(qm,b);  v[k] = Wk_h[k,:] . colsum(km,b)
  if (t < 128) {
    const int d = t & 63;
    const bf16* wrow = ((t < 64) ? Wq_h : Wk_h) + d * 512;
    const float* sv = colsum + (((t < 64) ? qm : km) * 8 + b) * 512;
    float a = 0.f;
    for (int c = 0; c < 512; c += 8) {
      const bfrag8 w8 = *(const bfrag8*)(wrow + c);
#pragma unroll
      for (int e = 0; e < 8; ++e) a += bf2f(w8[e]) * sv[c + e];
    }
    uv[t] = a;
  }

  // step A: R[512,64] = G . WB^T ; wave wv owns rows [wv*128, +128)
  f32x4 acc[8][4];
#pragma unroll
  for (int m = 0; m < 8; ++m)
#pragma unroll
    for (int n = 0; n < 4; ++n)
      acc[m][n] = f32x4{0.f, 0.f, 0.f, 0.f};
  for (int kk = 0; kk < 512; kk += 32) {
    bfrag8 a[8], bb[4];
#pragma unroll
    for (int m = 0; m < 8; ++m)
      a[m] = *(const bfrag8*)(G + (wv * 128 + m * 16 + l16) * 512 + kk + lk * 8);
#pragma unroll
    for (int n = 0; n < 4; ++n)
      bb[n] = *(const bfrag8*)(WB + (n * 16 + l16) * 512 + kk + lk * 8);
#pragma unroll
    for (int m = 0; m < 8; ++m)
#pragma unroll
      for (int n = 0; n < 4; ++n)
        mfma_bf16(acc[m][n], a[m], bb[n]);
  }
  // write R^T to LDS: Rt[col 64][row 512] pad 520
#pragma unroll
  for (int m = 0; m < 8; ++m)
#pragma unroll
    for (int n = 0; n < 4; ++n)
#pragma unroll
      for (int idx = 0; idx < 4; ++idx)
        RtS[(n * 16 + l16) * 520 + wv * 128 + m * 16 + lk * 4 + idx] =
            __float2bfloat16(acc[m][n][idx]);
  __syncthreads();

  // step B: S[64,64] = WA . Rt^T ; wave wv owns cols [wv*16, +16)
  f32x4 acc2[4];
#pragma unroll
  for (int m = 0; m < 4; ++m) acc2[m] = f32x4{0.f, 0.f, 0.f, 0.f};
  for (int kk = 0; kk < 512; kk += 32) {
    bfrag8 a2[4];
#pragma unroll
    for (int m = 0; m < 4; ++m)
      a2[m] = *(const bfrag8*)(WA + (m * 16 + l16) * 512 + kk + lk * 8);
    const bfrag8 b2 = *(const bfrag8*)(&RtS[(wv * 16 + l16) * 520 + kk + lk * 8]);
#pragma unroll
    for (int m = 0; m < 4; ++m) mfma_bf16(acc2[m], a2[m], b2);
  }
  __syncthreads();  // all waves done reading RtS
  float* S = (float*)RtS;  // [64][68]
#pragma unroll
  for (int m = 0; m < 4; ++m)
#pragma unroll
    for (int idx = 0; idx < 4; ++idx)
      S[(m * 16 + lk * 4 + idx) * 68 + wv * 16 + l16] = acc2[m][idx];
  __syncthreads();

  // softmax over k for fixed d=r ; trans: S holds S'[k,d] -> read S[k*68+r]
  const int r = t >> 2, q = t & 3;
  const float* bq_h = bq + i * 512 + h * 64;
  const float* bk_h = bk + i * 512 + h * 64;
  const float u_r = uv[r], bq_r = bq_h[r];
  float vals[16];
  float mx = -1e30f;
#pragma unroll
  for (int kq = 0; kq < 16; ++kq) {
    const int k = q * 16 + kq;
    float s = trans ? S[k * 68 + r] : S[r * 68 + k];
    s += u_r * bk_h[k] + bq_r * uv[64 + k] + 4096.0f * bq_r * bk_h[k];
    s *= 0.125f;
    vals[kq] = s;
    mx = fmaxf(mx, s);
  }
  mx = fmaxf(mx, __shfl_xor(mx, 1));
  mx = fmaxf(mx, __shfl_xor(mx, 2));
  float sum = 0.f;
#pragma unroll
  for (int kq = 0; kq < 16; ++kq) { vals[kq] = expf(vals[kq] - mx); sum += vals[kq]; }
  sum += __shfl_xor(sum, 1);
  sum += __shfl_xor(sum, 2);
  const float inv = 1.0f / sum;
  __align__(16) bf16 ob[16];
#pragma unroll
  for (int kq = 0; kq < 16; ++kq) ob[kq] = __float2bfloat16(vals[kq] * inv);
  bf16* op = attnB + (((long)(i * 8 + b) * 8 + h) * 64 + r) * 64 + q * 16;
  *(bfrag8*)(op) = *(const bfrag8*)(ob);
  *(bfrag8*)(op + 8) = *(const bfrag8*)(ob + 8);
}

// =================== PV: O'[p, d] = sum_e V'[p, e] * attn[d, e] ===================
__global__ __launch_bounds__(256, 2) void pv_kernel(
    const bf16* __restrict__ Vst, const bf16* __restrict__ attnB,
    bf16* __restrict__ Ost)
{
  __shared__ __align__(16) bf16 As[128 * 32];
  __shared__ __align__(16) bf16 Bs[64 * 32];
  const int i = blockIdx.z;
  const int qm = i >> 1, jj = i & 1;
  const int km = jj ? (qm == 2 ? 1 : 2) : (qm == 0 ? 1 : 0);
  const int slot = (i >= 3) ? 1 : 0;
  const int bh = blockIdx.y, b = bh >> 3, h = bh & 7;
  const bf16* A = Vst + (long)km * 33554432 + (long)b * 4096 * 1024 + slot * 512 + h * 64;
  const bf16* Bt = attnB + ((long)(i * 8 + b) * 8 + h) * 4096;
  f32x4 acc[4][2];
#pragma unroll
  for (int m = 0; m < 4; ++m)
#pragma unroll
    for (int n = 0; n < 2; ++n)
      acc[m][n] = f32x4{0.f, 0.f, 0.f, 0.f};
  const long m0 = (long)blockIdx.x * 128;
  gemm_core<128, 64>(A, 1024, Bt, 64, 64, m0, 0, As, Bs, acc);

  const int t = threadIdx.x;
  const int lane = t & 63, wv = t >> 6;
  const int wr = wv >> 1, wc = wv & 1;
  const int l16 = lane & 15, lk = lane >> 4;
  bf16* Cb = Ost + (long)qm * 33554432 + (long)b * 4096 * 1024 + jj * 512 + h * 64;
#pragma unroll
  for (int m = 0; m < 4; ++m) {
    const long gr0 = m0 + wr * 64 + m * 16 + lk * 4;
#pragma unroll
    for (int n = 0; n < 2; ++n) {
      const int gc = wc * 32 + n * 16 + l16;
#pragma unroll
      for (int i2 = 0; i2 < 4; ++i2)
        Cb[(gr0 + i2) * 1024 + gc] = __float2bfloat16(acc[m][n][i2]);
    }
  }
}

// =================== SE pooling / MLP ===================
__global__ __launch_bounds__(512) void se_pool(
    const float* __restrict__ c0, const float* __restrict__ c1,
    const float* __restrict__ c2, float* __restrict__ pooled)
{
  const int m = blockIdx.z, b = blockIdx.y, pc = blockIdx.x;
  const float* cr = (m == 0) ? c0 : (m == 1) ? c1 : c2;
  const int c = threadIdx.x;
  float s = 0.f;
  const float* base = cr + ((long)b * 4096 + pc * 512) * 512 + c;
  for (int pp = 0; pp < 512; ++pp) s += base[(long)pp * 512];
  atomicAdd(&pooled[((long)m * 8 + b) * 512 + c], s);
}

__global__ __launch_bounds__(512) void se_mlp(
    const float* __restrict__ pooled,
    const float* __restrict__ W1, const float* __restrict__ b1,
    const float* __restrict__ W2, const float* __restrict__ b2,
    float* __restrict__ se)
{
  const int b = blockIdx.x, m = blockIdx.y;
  __shared__ float y[32];
  const int t = threadIdx.x;
  if (t < 32) {
    float s = b1[m * 32 + t];
    const float* w = W1 + (long)(m * 32 + t) * 512;
    const float* p = pooled + ((long)m * 8 + b) * 512;
    for (int c = 0; c < 512; ++c) s += w[c] * (p[c] * (1.0f / 4096.0f));
    y[t] = fmaxf(s, 0.0f);
  }
  __syncthreads();
  float s = b2[m * 512 + t];
  const float* w2 = W2 + (long)(m * 512 + t) * 32;
#pragma unroll
  for (int j = 0; j < 32; ++j) s += w2[j] * y[j];
  se[((long)m * 8 + b) * 512 + t] = 1.0f / (1.0f + expf(-s));
}

// =================== refined = l2norm_c(cross * se) -> bf16 ===================
__global__ __launch_bounds__(256) void refine_kernel(
    const float* __restrict__ cr0, const float* __restrict__ cr1,
    const float* __restrict__ cr2, const float* __restrict__ se,
    bf16* __restrict__ rf0, bf16* __restrict__ rf1, bf16* __restrict__ rf2)
{
  const int g = blockIdx.x * 4 + (threadIdx.x >> 6);
  const int lane = threadIdx.x & 63;
  const int m = g >> 15;
  const int pix = g & 32767;
  const int b = pix >> 12;
  const float* cr = (m == 0) ? cr0 : (m == 1) ? cr1 : cr2;
  bf16* rf = (m == 0) ? rf0 : (m == 1) ? rf1 : rf2;
  const int c0 = lane * 8;
  const float4 v0 = *(const float4*)(cr + (long)pix * 512 + c0);
  const float4 v1 = *(const float4*)(cr + (long)pix * 512 + c0 + 4);
  const float* sp = se + ((long)m * 8 + b) * 512 + c0;
  const float4 s0 = *(const float4*)(sp);
  const float4 s1 = *(const float4*)(sp + 4);
  float w[8] = {v0.x * s0.x, v0.y * s0.y, v0.z * s0.z, v0.w * s0.w,
                v1.x * s1.x, v1.y * s1.y, v1.z * s1.z, v1.w * s1.w};
  float ss = 0.f;
#pragma unroll
  for (int i = 0; i < 8; ++i) ss += w[i] * w[i];
  for (int o = 32; o; o >>= 1) ss += __shfl_xor(ss, o);
  const float inv = 1.0f / (sqrtf(ss) + 1e-6f);
  __align__(16) bf16 tmp[8];
#pragma unroll
  for (int i = 0; i < 8; ++i) tmp[i] = __float2bfloat16(w[i] * inv);
  *(bfrag8*)(rf + (long)pix * 512 + c0) = *(const bfrag8*)tmp;
}

// =================== gate (alpha) + weighted concat ===================
__global__ __launch_bounds__(256) void gate_kernel(
    const bf16* __restrict__ rf0, const bf16* __restrict__ rf1,
    const bf16* __restrict__ rf2, const float* __restrict__ gw,
    const float* __restrict__ gb, const float* __restrict__ qacc,
    bf16* __restrict__ weighted)
{
  const int g = blockIdx.x * 4 + (threadIdx.x >> 6);
  const int lane = threadIdx.x & 63;
  const int b = g >> 12;
  const bf16* rfs[3] = {rf0, rf1, rf2};
  float a0 = 0.f, a1 = 0.f, a2 = 0.f;
#pragma unroll
  for (int m = 0; m < 3; ++m) {
    const bf16* rp = rfs[m] + (long)g * 512;
#pragma unroll
    for (int j = 0; j < 8; ++j) {
      const int c = j * 64 + lane;
      const float v = __bfloat162float(rp[c]);
      a0 += gw[0 * 1539 + m * 512 + c] * v;
      a1 += gw[1 * 1539 + m * 512 + c] * v;
      a2 += gw[2 * 1539 + m * 512 + c] * v;
    }
  }
  for (int o = 32; o; o >>= 1) {
    a0 += __shfl_xor(a0, o); a1 += __shfl_xor(a1, o); a2 += __shfl_xor(a2, o);
  }
  const float N = 2097152.0f;
  const float q0 = qacc[b * 4 + 0] / N;
  const float q1 = (qacc[b * 4 + 2] - qacc[b * 4 + 1] * qacc[b * 4 + 1] / N) / (N - 1.0f);
  const float q2 = qacc[b * 4 + 3] / N;
  float al[3];
  const float av[3] = {a0, a1, a2};
#pragma unroll
  for (int gg = 0; gg < 3; ++gg) {
    const float s = av[gg] + gb[gg] + gw[gg * 1539 + 1536] * q0 +
                    gw[gg * 1539 + 1537] * q1 + gw[gg * 1539 + 1538] * q2;
    al[gg] = 1.0f / (1.0f + expf(-s));
  }
#pragma unroll
  for (int m = 0; m < 3; ++m) {
    const bf16* rp = rfs[m] + (long)g * 512;
    bf16* wp = weighted + (long)g * 1536 + m * 512;
#pragma unroll
    for (int j = 0; j < 8; ++j) {
      const int c = j * 64 + lane;
      wp[c] = __float2bfloat16(__bfloat162float(rp[c]) * al[m]);
    }
  }
}

// =================== host launch ===================
extern "C" void kernel_launch(void* const* d_in, const int* in_sizes, int n_in,
                              void* d_out, int out_size, void* d_ws, size_t ws_size,
                              hipStream_t stream)
{
  (void)in_sizes; (void)n_in; (void)out_size; (void)ws_size;
  const float* rgb   = (const float*)d_in[0];
  const float* depth = (const float*)d_in[1];
  const float* lidar = (const float*)d_in[2];
  const float* wq  = (const float*)d_in[3];
  const float* bq  = (const float*)d_in[4];
  const float* wk  = (const float*)d_in[5];
  const float* bk  = (const float*)d_in[6];
  const float* wvw = (const float*)d_in[7];
  const float* bv  = (const float*)d_in[8];
  const float* wo  = (const float*)d_in[9];
  const float* bo  = (const float*)d_in[10];
  const float* seW1 = (const float*)d_in[11];
  const float* seb1 = (const float*)d_in[12];
  const float* seW2 = (const float*)d_in[13];
  const float* seb2 = (const float*)d_in[14];
  const float* gw  = (const float*)d_in[15];
  const float* gb  = (const float*)d_in[16];
  const float* fw  = (const float*)d_in[17];
  const float* fb  = (const float*)d_in[18];

  char* ws = (char*)d_ws;
  bf16*  xT   = (bf16*)(ws + OFF_XT);
  bf16*  xC   = (bf16*)(ws + OFF_XC);
  bf16*  wqB  = (bf16*)(ws + OFF_WQ);
  bf16*  wkB  = (bf16*)(ws + OFF_WK);
  bf16*  wv2  = (bf16*)(ws + OFF_WV2);
  bf16*  wo2  = (bf16*)(ws + OFF_WO2);
  bf16*  fwB  = (bf16*)(ws + OFF_FW);
  float* bo2  = (float*)(ws + OFF_BO2);
  float* bv2  = (float*)(ws + OFF_BV2);
  float* pooled = (float*)(ws + OFF_POOL);
  float* seB  = (float*)(ws + OFF_SE);
  float* qacc = (float*)(ws + OFF_QACC);
  float* cs   = (float*)(ws + OFF_CS);
  bf16*  Gb   = (bf16*)(ws + OFF_GB);
  bf16*  attnB = (bf16*)(ws + OFF_ATT);
  bf16*  Vst  = (bf16*)(ws + OFF_VST);
  bf16*  Ost  = (bf16*)(ws + OFF_XT);        // alias after xT/xC dead

  // zero: pooled, se, qacc, colsum
  (void)hipMemsetAsync(ws + OFF_POOL, 0, OFF_CS + 49152 - OFF_POOL, stream);

  transpose_kernel<<<dim3(128, 16, 24), dim3(32, 8), 0, stream>>>(rgb, depth, lidar, xT, xC);
  prep_weights<<<2048, 256, 0, stream>>>(wq, wk, wvw, wo, fw, bo, bv,
                                         wqB, wkB, wv2, wo2, fwB, bo2, bv2);
  quality_kernel<<<dim3(32, 8, 3), 256, 0, stream>>>(rgb, depth, lidar, qacc);
  colsum_kernel<<<dim3(16, 8, 3), 256, 0, stream>>>(xT, cs);

  gram_kernel<<<dim3(4, 4, 24), 256, 0, stream>>>(xC, Gb);
  scores_kernel<<<dim3(8, 8, 6), 256, 0, stream>>>(wqB, wkB, Gb, cs, bq, bk, attnB);

  for (int m = 0; m < 3; ++m)
    gemm_bt<1><<<dim3(256, 8), 256, 0, stream>>>(xT + (long)m * 16777216, 512,
                                                 wv2 + (long)m * 524288, 512,
                                                 Vst + (long)m * 33554432, 1024, 512,
                                                 bv2 + m * 1024, nullptr);

  pv_kernel<<<dim3(32, 64, 6), 256, 0, stream>>>(Vst, attnB, Ost);

  float* cross[3];
  for (int m = 0; m < 3; ++m) cross[m] = (float*)(ws + OFF_VST + (long)m * 67108864);
  for (int m = 0; m < 3; ++m)
    gemm_bt<2><<<dim3(256, 4), 256, 0, stream>>>(Ost + (long)m * 33554432, 1024,
                                                 wo2 + (long)m * 524288, 1024,
                                                 cross[m], 512, 1024,
                                                 bo2 + m * 512, (const float*)d_in[m]);

  se_pool<<<dim3(8, 8, 3), 512, 0, stream>>>(cross[0], cross[1], cross[2], pooled);
  se_mlp<<<dim3(8, 3), 512, 0, stream>>>(pooled, seW1, seb1, seW2, seb2, seB);

  bf16* rf0 = (bf16*)(ws + 0L);
  bf16* rf1 = (bf16*)(ws + 33554432L);
  bf16* rf2 = (bf16*)(ws + 67108864L);
  refine_kernel<<<24576, 256, 0, stream>>>(cross[0], cross[1], cross[2], seB, rf0, rf1, rf2);

  bf16* weighted = (bf16*)(ws + 100663296L);
  gate_kernel<<<8192, 256, 0, stream>>>(rf0, rf1, rf2, gw, gb, qacc, weighted);

  gemm_bt<3><<<dim3(256, 12), 256, 0, stream>>>(weighted, 1536, fwB, 1536,
                                                d_out, 1536, 1536, fb, nullptr);
}